// Round 6
// baseline (1557.655 us; speedup 1.0000x reference)
//
#include <hip/hip_runtime.h>
#include <hip/hip_bf16.h>
#include <math.h>

#define N_FEAT 6272
#define DIM    128
#define M_BANK 30000
#define M_PAD  30080
#define NB     8
#define PH     28
#define PW     28
#define IMG    224
#define BM     256      // 4 waves x 64 rows (2 m-blocks of 32)
#define BN     128      // bank cols per LDS tile
#define TPC    5
#define CHUNKS 47       // 47*5*128 = 30080
#define TILE_BYTES 32768

typedef __attribute__((ext_vector_type(8)))  __bf16 bf16x8_t;
typedef __attribute__((ext_vector_type(2)))  __bf16 bf16x2_t;
typedef __attribute__((ext_vector_type(16))) float  f32x16_t;
typedef __attribute__((ext_vector_type(4)))  float  f32x4_t;
typedef __attribute__((ext_vector_type(2)))  float  f32x2_t;

typedef const __attribute__((address_space(1))) unsigned int g_u32;
typedef __attribute__((address_space(3))) unsigned int l_u32;

// Bank prep: fp32 -> bf16, retiled into MFMA B-fragment order.
// Layout: tile t (128 cols) | k-slice s = k>>3 (16 slices) | col c (128) | 8 bf16.
// byte addr = t*32768 + s*2048 + c*16. Also per-row sum-of-squares (+inf pad).
__global__ __launch_bounds__(256) void prep_bank(const float* __restrict__ src,
                                                 unsigned char* __restrict__ mbt,
                                                 float* __restrict__ sq) {
    const int tid  = threadIdx.x;
    const int s    = tid & 15;          // k-slice
    const int rloc = tid >> 4;          // 16 rows per block
    const int r    = blockIdx.x * 16 + rloc;
    const bool valid = r < M_BANK;
    float x[8];
    if (valid) {
        f32x4_t v0 = *(const f32x4_t*)(src + (size_t)r * DIM + s * 8);
        f32x4_t v1 = *(const f32x4_t*)(src + (size_t)r * DIM + s * 8 + 4);
        x[0]=v0.x; x[1]=v0.y; x[2]=v0.z; x[3]=v0.w;
        x[4]=v1.x; x[5]=v1.y; x[6]=v1.z; x[7]=v1.w;
    } else {
        #pragma unroll
        for (int e = 0; e < 8; ++e) x[e] = 0.f;
    }
    float sum = 0.f;
    #pragma unroll
    for (int e = 0; e < 8; ++e) sum += x[e] * x[e];
    sum += __shfl_xor(sum, 1);
    sum += __shfl_xor(sum, 2);
    sum += __shfl_xor(sum, 4);
    sum += __shfl_xor(sum, 8);
    bf16x8_t p;
    #pragma unroll
    for (int e = 0; e < 8; ++e) p[e] = (__bf16)x[e];
    const size_t addr = (size_t)(r >> 7) * TILE_BYTES + s * 2048 + (r & 127) * 16;
    *(bf16x8_t*)(mbt + addr) = p;
    if (s == 0) sq[r] = valid ? sum : INFINITY;
}

// Feature prep: row-major bf16 + sum-of-squares + nn init (one wave per row).
__global__ __launch_bounds__(256) void prep_feat(const float* __restrict__ src,
                                                 __bf16* __restrict__ dst,
                                                 float* __restrict__ sq,
                                                 unsigned int* __restrict__ nn) {
    int wave = (blockIdx.x * blockDim.x + threadIdx.x) >> 6;
    int lane = threadIdx.x & 63;
    if (wave >= N_FEAT) return;
    f32x2_t v = *(const f32x2_t*)(src + (size_t)wave * DIM + lane * 2);
    float s = v.x * v.x + v.y * v.y;
    #pragma unroll
    for (int m = 1; m < 64; m <<= 1) s += __shfl_xor(s, m);
    bf16x2_t p; p.x = (__bf16)v.x; p.y = (__bf16)v.y;
    *(bf16x2_t*)(dst + (size_t)wave * DIM + lane * 2) = p;
    if (lane == 0) { sq[wave] = s; nn[wave] = 0x7f800000u; }
}

static __device__ __forceinline__ f32x16_t zero16() {
    f32x16_t z;
    #pragma unroll
    for (int j = 0; j < 16; ++j) z[j] = 0.f;
    return z;
}

// Counted-vmcnt double-buffered dist+min. 4 waves x 64 rows (32x32 m=2).
// Raw s_barrier + s_waitcnt vmcnt(8): tile t+2's stage loads stay in flight
// across barriers (T3/T4). All other global reads hoisted before the first
// STAGE so no compiler wait drains the stage queue. Full t/n unroll for ILP.
__global__ __launch_bounds__(256, 2) void dist_min_kernel(
        const __bf16* __restrict__ fbb, const unsigned char* __restrict__ mbt,
        const float* __restrict__ f2, const float* __restrict__ m2,
        unsigned int* __restrict__ nn) {
    __shared__ __align__(16) unsigned char lds[2 * TILE_BYTES];
    const int tid  = threadIdx.x;
    const int lane = tid & 63;
    const int w    = tid >> 6;
    const int c32  = lane & 31;    // MFMA col / A-row within 32-block
    const int h    = lane >> 5;    // k-half selector
    const int arow = blockIdx.x * BM + w * 64;
    const int tile0 = blockIdx.y * TPC;

    // ---- all non-stage global reads FIRST (oldest in vmcnt FIFO) ----
    float m2v[TPC][4];
    #pragma unroll
    for (int t = 0; t < TPC; ++t)
        #pragma unroll
        for (int n = 0; n < 4; ++n)
            m2v[t][n] = m2[(tile0 + t) * BN + n * 32 + c32];

    int row0 = arow + c32;          if (row0 >= N_FEAT) row0 = N_FEAT - 1;
    int row1 = arow + 32 + c32;     if (row1 >= N_FEAT) row1 = N_FEAT - 1;
    float f2v0 = f2[arow + (0 & 3) + 0];  // placeholder ordering; real f2 in epilogue rows
    (void)f2v0;

    bf16x8_t afrag[2][8];
    #pragma unroll
    for (int kk = 0; kk < 8; ++kk) {
        afrag[0][kk] = *(const bf16x8_t*)(fbb + (size_t)row0 * DIM + kk * 16 + h * 8);
        afrag[1][kk] = *(const bf16x8_t*)(fbb + (size_t)row1 * DIM + kk * 16 + h * 8);
    }
    // f2 values for the 32 output rows this lane may publish (epilogue uses
    // rows arow + m*32 + crow; load the two this lane's (c32==0,h,j) can hit).
    float f2e[2][16];
    #pragma unroll
    for (int m = 0; m < 2; ++m)
        #pragma unroll
        for (int j = 0; j < 16; ++j) {
            int row = arow + m * 32 + (j & 3) + 8 * (j >> 2) + 4 * h;
            f2e[m][j] = f2[row < N_FEAT ? row : N_FEAT - 1];
        }

    f32x16_t rmin0 = zero16(), rmin1 = zero16();
    #pragma unroll
    for (int j = 0; j < 16; ++j) { rmin0[j] = INFINITY; rmin1[j] = INFINITY; }

    // ---- stage macro: 32KB tile, linear global -> linear LDS ----
#define STAGE(tile_idx, bufsel)                                                   \
    {   const unsigned char* sp_ = mbt + (size_t)(tile_idx) * TILE_BYTES + tid * 16; \
        unsigned char* dp_ = lds + (bufsel) * TILE_BYTES + tid * 16;              \
        _Pragma("unroll")                                                         \
        for (int i_ = 0; i_ < 8; ++i_)                                            \
            __builtin_amdgcn_global_load_lds((g_u32*)(sp_ + i_ * 4096),           \
                                             (l_u32*)(dp_ + i_ * 4096), 16, 0, 0); }

    // prologue: 2-deep prefetch
    STAGE(tile0 + 0, 0);
    STAGE(tile0 + 1, 1);
    asm volatile("s_waitcnt vmcnt(8)" ::: "memory");   // tile0 landed; tile1 in flight
    asm volatile("s_barrier" ::: "memory");

    #pragma unroll
    for (int t = 0; t < TPC; ++t) {
        const unsigned char* bufp = lds + (t & 1) * TILE_BYTES;
        #pragma unroll
        for (int n = 0; n < 4; ++n) {
            bf16x8_t b[8];
            #pragma unroll
            for (int kk = 0; kk < 8; ++kk)
                b[kk] = *(const bf16x8_t*)(bufp + (kk * 2 + h) * 2048 + n * 512 + c32 * 16);
            f32x16_t acc0 = zero16(), acc1 = zero16();
            __builtin_amdgcn_s_setprio(1);
            #pragma unroll
            for (int kk = 0; kk < 8; ++kk) {
                acc0 = __builtin_amdgcn_mfma_f32_32x32x16_bf16(afrag[0][kk], b[kk], acc0, 0, 0, 0);
                acc1 = __builtin_amdgcn_mfma_f32_32x32x16_bf16(afrag[1][kk], b[kk], acc1, 0, 0, 0);
            }
            __builtin_amdgcn_s_setprio(0);
            #pragma unroll
            for (int j = 0; j < 16; ++j) {
                rmin0[j] = fminf(rmin0[j], fmaf(-2.f, acc0[j], m2v[t][n]));
                rmin1[j] = fminf(rmin1[j], fmaf(-2.f, acc1[j], m2v[t][n]));
            }
        }
        if (t + 1 < TPC) {
            asm volatile("s_barrier" ::: "memory");        // B1: all waves done reading buf[t&1]
            if (t + 2 < TPC) {
                STAGE(tile0 + t + 2, t & 1);
                asm volatile("s_waitcnt vmcnt(8)" ::: "memory");  // t+1 landed; t+2 in flight
            } else {
                asm volatile("s_waitcnt vmcnt(0)" ::: "memory");  // last prefetch: t+1 landed
            }
            asm volatile("s_barrier" ::: "memory");        // B2: buf[(t+1)&1] ready for all
        }
    }
#undef STAGE

    // Epilogue: min across the 32 col-lanes (xor 1..16 stays within same h),
    // add f2, one atomic per row.
    #pragma unroll
    for (int m = 0; m < 2; ++m) {
        #pragma unroll
        for (int j = 0; j < 16; ++j) {
            float v = m ? rmin1[j] : rmin0[j];
            v = fminf(v, __shfl_xor(v, 1));
            v = fminf(v, __shfl_xor(v, 2));
            v = fminf(v, __shfl_xor(v, 4));
            v = fminf(v, __shfl_xor(v, 8));
            v = fminf(v, __shfl_xor(v, 16));
            if (c32 == 0) {
                int row = arow + m * 32 + (j & 3) + 8 * (j >> 2) + 4 * h;
                if (row < N_FEAT)
                    atomicMin(nn + row, __float_as_uint(v + f2e[m][j]));
            }
        }
    }
}

__global__ void image_max_kernel(const unsigned int* __restrict__ nn,
                                 float* __restrict__ out) {
    __shared__ float wmax[4];
    int b = blockIdx.x;
    int tid = threadIdx.x;
    float v = -INFINITY;
    for (int i = tid; i < PH * PW; i += 256)
        v = fmaxf(v, __uint_as_float(nn[b * PH * PW + i]));
    #pragma unroll
    for (int m = 1; m < 64; m <<= 1) v = fmaxf(v, __shfl_xor(v, m));
    if ((tid & 63) == 0) wmax[tid >> 6] = v;
    __syncthreads();
    if (tid == 0) out[b] = fmaxf(fmaxf(wmax[0], wmax[1]), fmaxf(wmax[2], wmax[3]));
}

// Half-pixel bilinear 28x28 -> 224x224 with edge clamp (== jax bilinear resize).
__global__ void upsample_kernel(const unsigned int* __restrict__ nn,
                                float* __restrict__ up) {
    int idx = blockIdx.x * 256 + threadIdx.x;
    if (idx >= NB * IMG * IMG) return;
    int b = idx / (IMG * IMG);
    int rem = idx - b * (IMG * IMG);
    int y = rem / IMG;
    int x = rem - y * IMG;
    float sy = y * 0.125f - 0.4375f;
    float sx = x * 0.125f - 0.4375f;
    float fy = floorf(sy), fx = floorf(sx);
    float ty = sy - fy, tx = sx - fx;
    int y0 = (int)fy, x0 = (int)fx;
    int y1 = min(y0 + 1, PH - 1), x1 = min(x0 + 1, PW - 1);
    y0 = max(y0, 0); x0 = max(x0, 0);
    const unsigned int* p = nn + b * PH * PW;
    float v00 = __uint_as_float(p[y0 * PW + x0]);
    float v01 = __uint_as_float(p[y0 * PW + x1]);
    float v10 = __uint_as_float(p[y1 * PW + x0]);
    float v11 = __uint_as_float(p[y1 * PW + x1]);
    float v0 = v00 + tx * (v01 - v00);
    float v1 = v10 + tx * (v11 - v10);
    up[idx] = v0 + ty * (v1 - v0);
}

extern "C" void kernel_launch(void* const* d_in, const int* in_sizes, int n_in,
                              void* d_out, int out_size, void* d_ws, size_t ws_size,
                              hipStream_t stream) {
    const float* feat = (const float*)d_in[0];   // [6272,128] f32
    const float* bank = (const float*)d_in[1];   // [30000,128] f32
    char* ws = (char*)d_ws;
    unsigned char* mbt = (unsigned char*)(ws + 0);     // 30080*128*2 = 7,700,480 (tiled)
    __bf16*        fbb = (__bf16*)(ws + 7700480);      // 6272*128*2  = 1,605,632
    float*         m2  = (float*)(ws + 9306112);       // 30080*4
    float*         f2  = (float*)(ws + 9426432);       // 6272*4
    unsigned int*  nn  = (unsigned int*)(ws + 9451520);// 6272*4
    float* out_scores = (float*)d_out;                 // [8]
    float* out_up     = out_scores + NB;               // [8,224,224]

    hipLaunchKernelGGL(prep_bank, dim3(M_PAD / 16), dim3(256), 0, stream, bank, mbt, m2);
    hipLaunchKernelGGL(prep_feat, dim3(N_FEAT / 4), dim3(256), 0, stream, feat, fbb, f2, nn);
    hipLaunchKernelGGL(dist_min_kernel, dim3((N_FEAT + BM - 1) / BM, CHUNKS), dim3(256), 0,
                       stream, fbb, mbt, f2, m2, nn);
    hipLaunchKernelGGL(image_max_kernel, dim3(NB), dim3(256), 0, stream, nn, out_scores);
    hipLaunchKernelGGL(upsample_kernel, dim3((NB * IMG * IMG + 255) / 256), dim3(256), 0,
                       stream, nn, out_up);
}

// Round 7
// 106.245 us; speedup vs baseline: 14.6610x; 14.6610x over previous
//
#include <hip/hip_runtime.h>
#include <hip/hip_bf16.h>
#include <math.h>

#define N_FEAT 6272
#define DIM    128
#define M_BANK 30000
#define M_PAD  30080
#define NB     8
#define PH     28
#define PW     28
#define IMG    224
#define BN     128      // bank cols per tile
#define TPC    5
#define CHUNKS 47       // 47*5*128 = 30080
#define TILE_BYTES 32768

typedef __attribute__((ext_vector_type(8)))  __bf16 bf16x8_t;
typedef __attribute__((ext_vector_type(2)))  __bf16 bf16x2_t;
typedef __attribute__((ext_vector_type(16))) float  f32x16_t;
typedef __attribute__((ext_vector_type(4)))  float  f32x4_t;
typedef __attribute__((ext_vector_type(2)))  float  f32x2_t;

// Bank prep: fp32 -> bf16, retiled into MFMA B-fragment order.
// Layout: tile t (128 cols) | k-slice s = k>>3 (16 slices) | col c (128) | 8 bf16.
// byte addr = t*32768 + s*2048 + c*16. Also per-row sum-of-squares (+inf pad).
__global__ __launch_bounds__(256) void prep_bank(const float* __restrict__ src,
                                                 unsigned char* __restrict__ mbt,
                                                 float* __restrict__ sq) {
    const int tid  = threadIdx.x;
    const int s    = tid & 15;          // k-slice
    const int rloc = tid >> 4;          // 16 rows per block
    const int r    = blockIdx.x * 16 + rloc;
    const bool valid = r < M_BANK;
    float x[8];
    if (valid) {
        f32x4_t v0 = *(const f32x4_t*)(src + (size_t)r * DIM + s * 8);
        f32x4_t v1 = *(const f32x4_t*)(src + (size_t)r * DIM + s * 8 + 4);
        x[0]=v0.x; x[1]=v0.y; x[2]=v0.z; x[3]=v0.w;
        x[4]=v1.x; x[5]=v1.y; x[6]=v1.z; x[7]=v1.w;
    } else {
        #pragma unroll
        for (int e = 0; e < 8; ++e) x[e] = 0.f;
    }
    float sum = 0.f;
    #pragma unroll
    for (int e = 0; e < 8; ++e) sum += x[e] * x[e];
    sum += __shfl_xor(sum, 1);
    sum += __shfl_xor(sum, 2);
    sum += __shfl_xor(sum, 4);
    sum += __shfl_xor(sum, 8);
    bf16x8_t p;
    #pragma unroll
    for (int e = 0; e < 8; ++e) p[e] = (__bf16)x[e];
    const size_t addr = (size_t)(r >> 7) * TILE_BYTES + s * 2048 + (r & 127) * 16;
    *(bf16x8_t*)(mbt + addr) = p;
    if (s == 0) sq[r] = valid ? sum : INFINITY;
}

// Feature prep: row-major bf16 + sum-of-squares + nn init (one wave per row).
__global__ __launch_bounds__(256) void prep_feat(const float* __restrict__ src,
                                                 __bf16* __restrict__ dst,
                                                 float* __restrict__ sq,
                                                 unsigned int* __restrict__ nn) {
    int wave = (blockIdx.x * blockDim.x + threadIdx.x) >> 6;
    int lane = threadIdx.x & 63;
    if (wave >= N_FEAT) return;
    f32x2_t v = *(const f32x2_t*)(src + (size_t)wave * DIM + lane * 2);
    float s = v.x * v.x + v.y * v.y;
    #pragma unroll
    for (int m = 1; m < 64; m <<= 1) s += __shfl_xor(s, m);
    bf16x2_t p; p.x = (__bf16)v.x; p.y = (__bf16)v.y;
    *(bf16x2_t*)(dst + (size_t)wave * DIM + lane * 2) = p;
    if (lane == 0) { sq[wave] = s; nn[wave] = 0x7f800000u; }
}

static __device__ __forceinline__ f32x16_t zero16() {
    f32x16_t z;
    #pragma unroll
    for (int j = 0; j < 16; ++j) z[j] = 0.f;
    return z;
}

// Barrier-free dist+min: NO LDS, NO staging. The pre-tiled bank (7.7MB) is
// L2/L3-resident; each 64-row wave streams B-fragments straight into
// registers (32 x dwordx4 per 128-col tile) and feeds 32x32x16 MFMA m=2.
// Pipes: L2-read ~21.9us, MFMA ~19.4us, fold ~7us -- overlapped via n-level
// ILP + 2 waves/SIMD TLP, with no sync points to serialize them.
__global__ __launch_bounds__(128, 2) void dist_min_kernel(
        const __bf16* __restrict__ fbb, const unsigned char* __restrict__ mbt,
        const float* __restrict__ f2, const float* __restrict__ m2,
        unsigned int* __restrict__ nn) {
    const int lane = threadIdx.x & 63;
    const int w    = threadIdx.x >> 6;   // 0..1
    const int c32  = lane & 31;          // MFMA col / A-row within 32-block
    const int h    = lane >> 5;          // k-half selector
    const int arow = blockIdx.x * 128 + w * 64;   // 49*128 = 6272 exact
    const int tile0 = blockIdx.y * TPC;

    // A fragments: afrag[m][kk] = A[arow+m*32+c32][kk*16 + h*8 .. +7]
    bf16x8_t afrag[2][8];
    #pragma unroll
    for (int m = 0; m < 2; ++m)
        #pragma unroll
        for (int kk = 0; kk < 8; ++kk)
            afrag[m][kk] = *(const bf16x8_t*)(fbb + (size_t)(arow + m * 32 + c32) * DIM
                                              + kk * 16 + h * 8);

    const f32x16_t zacc = zero16();      // persistent zero C-input
    f32x16_t rmin0, rmin1;
    #pragma unroll
    for (int j = 0; j < 16; ++j) { rmin0[j] = INFINITY; rmin1[j] = INFINITY; }

    #pragma unroll 1
    for (int t = 0; t < TPC; ++t) {
        const unsigned char* base = mbt + (size_t)(tile0 + t) * TILE_BYTES;
        const float* m2p = m2 + (size_t)(tile0 + t) * BN;
        #pragma unroll
        for (int n = 0; n < 4; ++n) {
            const float m2c = m2p[n * 32 + c32];
            bf16x8_t b[8];
            #pragma unroll
            for (int kk = 0; kk < 8; ++kk)
                b[kk] = *(const bf16x8_t*)(base + (kk * 2 + h) * 2048 + n * 512 + c32 * 16);
            f32x16_t acc0 = __builtin_amdgcn_mfma_f32_32x32x16_bf16(afrag[0][0], b[0], zacc, 0, 0, 0);
            f32x16_t acc1 = __builtin_amdgcn_mfma_f32_32x32x16_bf16(afrag[1][0], b[0], zacc, 0, 0, 0);
            #pragma unroll
            for (int kk = 1; kk < 8; ++kk) {
                acc0 = __builtin_amdgcn_mfma_f32_32x32x16_bf16(afrag[0][kk], b[kk], acc0, 0, 0, 0);
                acc1 = __builtin_amdgcn_mfma_f32_32x32x16_bf16(afrag[1][kk], b[kk], acc1, 0, 0, 0);
            }
            #pragma unroll
            for (int j = 0; j < 16; ++j) {
                rmin0[j] = fminf(rmin0[j], fmaf(-2.f, acc0[j], m2c));
                rmin1[j] = fminf(rmin1[j], fmaf(-2.f, acc1[j], m2c));
            }
        }
    }

    // Epilogue: min across the 32 col-lanes (xor 1..16 stays within same h),
    // add f2, one atomic per row. Row range is exact (no tail).
    #pragma unroll
    for (int m = 0; m < 2; ++m) {
        #pragma unroll
        for (int j = 0; j < 16; ++j) {
            float v = m ? rmin1[j] : rmin0[j];
            v = fminf(v, __shfl_xor(v, 1));
            v = fminf(v, __shfl_xor(v, 2));
            v = fminf(v, __shfl_xor(v, 4));
            v = fminf(v, __shfl_xor(v, 8));
            v = fminf(v, __shfl_xor(v, 16));
            if (c32 == 0) {
                int row = arow + m * 32 + (j & 3) + 8 * (j >> 2) + 4 * h;
                atomicMin(nn + row, __float_as_uint(v + f2[row]));
            }
        }
    }
}

__global__ void image_max_kernel(const unsigned int* __restrict__ nn,
                                 float* __restrict__ out) {
    __shared__ float wmax[4];
    int b = blockIdx.x;
    int tid = threadIdx.x;
    float v = -INFINITY;
    for (int i = tid; i < PH * PW; i += 256)
        v = fmaxf(v, __uint_as_float(nn[b * PH * PW + i]));
    #pragma unroll
    for (int m = 1; m < 64; m <<= 1) v = fmaxf(v, __shfl_xor(v, m));
    if ((tid & 63) == 0) wmax[tid >> 6] = v;
    __syncthreads();
    if (tid == 0) out[b] = fmaxf(fmaxf(wmax[0], wmax[1]), fmaxf(wmax[2], wmax[3]));
}

// Half-pixel bilinear 28x28 -> 224x224 with edge clamp (== jax bilinear resize).
__global__ void upsample_kernel(const unsigned int* __restrict__ nn,
                                float* __restrict__ up) {
    int idx = blockIdx.x * 256 + threadIdx.x;
    if (idx >= NB * IMG * IMG) return;
    int b = idx / (IMG * IMG);
    int rem = idx - b * (IMG * IMG);
    int y = rem / IMG;
    int x = rem - y * IMG;
    float sy = y * 0.125f - 0.4375f;
    float sx = x * 0.125f - 0.4375f;
    float fy = floorf(sy), fx = floorf(sx);
    float ty = sy - fy, tx = sx - fx;
    int y0 = (int)fy, x0 = (int)fx;
    int y1 = min(y0 + 1, PH - 1), x1 = min(x0 + 1, PW - 1);
    y0 = max(y0, 0); x0 = max(x0, 0);
    const unsigned int* p = nn + b * PH * PW;
    float v00 = __uint_as_float(p[y0 * PW + x0]);
    float v01 = __uint_as_float(p[y0 * PW + x1]);
    float v10 = __uint_as_float(p[y1 * PW + x0]);
    float v11 = __uint_as_float(p[y1 * PW + x1]);
    float v0 = v00 + tx * (v01 - v00);
    float v1 = v10 + tx * (v11 - v10);
    up[idx] = v0 + ty * (v1 - v0);
}

extern "C" void kernel_launch(void* const* d_in, const int* in_sizes, int n_in,
                              void* d_out, int out_size, void* d_ws, size_t ws_size,
                              hipStream_t stream) {
    const float* feat = (const float*)d_in[0];   // [6272,128] f32
    const float* bank = (const float*)d_in[1];   // [30000,128] f32
    char* ws = (char*)d_ws;
    unsigned char* mbt = (unsigned char*)(ws + 0);     // 30080*128*2 = 7,700,480 (tiled)
    __bf16*        fbb = (__bf16*)(ws + 7700480);      // 6272*128*2  = 1,605,632
    float*         m2  = (float*)(ws + 9306112);       // 30080*4
    float*         f2  = (float*)(ws + 9426432);       // 6272*4
    unsigned int*  nn  = (unsigned int*)(ws + 9451520);// 6272*4
    float* out_scores = (float*)d_out;                 // [8]
    float* out_up     = out_scores + NB;               // [8,224,224]

    hipLaunchKernelGGL(prep_bank, dim3(M_PAD / 16), dim3(256), 0, stream, bank, mbt, m2);
    hipLaunchKernelGGL(prep_feat, dim3(N_FEAT / 4), dim3(256), 0, stream, feat, fbb, f2, nn);
    hipLaunchKernelGGL(dist_min_kernel, dim3(N_FEAT / 128, CHUNKS), dim3(128), 0,
                       stream, fbb, mbt, f2, m2, nn);
    hipLaunchKernelGGL(image_max_kernel, dim3(NB), dim3(256), 0, stream, nn, out_scores);
    hipLaunchKernelGGL(upsample_kernel, dim3((NB * IMG * IMG + 255) / 256), dim3(256), 0,
                       stream, nn, out_up);
}

// Round 8
// 85.611 us; speedup vs baseline: 18.1947x; 1.2410x over previous
//
#include <hip/hip_runtime.h>
#include <hip/hip_bf16.h>
#include <math.h>

#define N_FEAT 6272
#define DIM    128
#define M_BANK 30000
#define M_PAD  30080
#define NB     8
#define PH     28
#define PW     28
#define IMG    224
#define BM     256      // 4 waves x 64 rows (4 mb-blocks of 16)
#define BN     128      // bank cols per LDS tile
#define TPC    5
#define CHUNKS 47       // 47*5*128 = 30080
#define TILE_BYTES 32768

typedef __attribute__((ext_vector_type(8)))  __bf16 bf16x8_t;
typedef __attribute__((ext_vector_type(2)))  __bf16 bf16x2_t;
typedef __attribute__((ext_vector_type(4)))  float  f32x4_t;
typedef __attribute__((ext_vector_type(2)))  float  f32x2_t;

typedef const __attribute__((address_space(1))) unsigned int g_u32;
typedef __attribute__((address_space(3))) unsigned int l_u32;

// Bank prep: fp32 -> bf16, retiled into MFMA B-fragment order.
// Layout: tile t (128 cols) | k-slice s = k>>3 (16 slices) | col c (128) | 8 bf16.
// byte addr = t*32768 + s*2048 + c*16. Also per-row sum-of-squares (+inf pad).
__global__ __launch_bounds__(256) void prep_bank(const float* __restrict__ src,
                                                 unsigned char* __restrict__ mbt,
                                                 float* __restrict__ sq) {
    const int tid  = threadIdx.x;
    const int s    = tid & 15;          // k-slice
    const int rloc = tid >> 4;          // 16 rows per block
    const int r    = blockIdx.x * 16 + rloc;
    const bool valid = r < M_BANK;
    float x[8];
    if (valid) {
        f32x4_t v0 = *(const f32x4_t*)(src + (size_t)r * DIM + s * 8);
        f32x4_t v1 = *(const f32x4_t*)(src + (size_t)r * DIM + s * 8 + 4);
        x[0]=v0.x; x[1]=v0.y; x[2]=v0.z; x[3]=v0.w;
        x[4]=v1.x; x[5]=v1.y; x[6]=v1.z; x[7]=v1.w;
    } else {
        #pragma unroll
        for (int e = 0; e < 8; ++e) x[e] = 0.f;
    }
    float sum = 0.f;
    #pragma unroll
    for (int e = 0; e < 8; ++e) sum += x[e] * x[e];
    sum += __shfl_xor(sum, 1);
    sum += __shfl_xor(sum, 2);
    sum += __shfl_xor(sum, 4);
    sum += __shfl_xor(sum, 8);
    bf16x8_t p;
    #pragma unroll
    for (int e = 0; e < 8; ++e) p[e] = (__bf16)x[e];
    const size_t addr = (size_t)(r >> 7) * TILE_BYTES + s * 2048 + (r & 127) * 16;
    *(bf16x8_t*)(mbt + addr) = p;
    if (s == 0) sq[r] = valid ? sum : INFINITY;
}

// Feature prep: row-major bf16 + sum-of-squares + nn init (one wave per row).
__global__ __launch_bounds__(256) void prep_feat(const float* __restrict__ src,
                                                 __bf16* __restrict__ dst,
                                                 float* __restrict__ sq,
                                                 unsigned int* __restrict__ nn) {
    int wave = (blockIdx.x * blockDim.x + threadIdx.x) >> 6;
    int lane = threadIdx.x & 63;
    if (wave >= N_FEAT) return;
    f32x2_t v = *(const f32x2_t*)(src + (size_t)wave * DIM + lane * 2);
    float s = v.x * v.x + v.y * v.y;
    #pragma unroll
    for (int m = 1; m < 64; m <<= 1) s += __shfl_xor(s, m);
    bf16x2_t p; p.x = (__bf16)v.x; p.y = (__bf16)v.y;
    *(bf16x2_t*)(dst + (size_t)wave * DIM + lane * 2) = p;
    if (lane == 0) { sq[wave] = s; nn[wave] = 0x7f800000u; }
}

// r4 skeleton, doubled rows/wave: 4 waves x 64 rows (4 mb-blocks of 16),
// 16x16x32 MFMA, single 32KB LDS buffer, 2 barriers/tile, full n-unroll.
// Halves LDS-read traffic vs r4 (14.5us floor) while keeping short 4-deep
// chains x4 independent. ~150 regs -> 3 waves/SIMD, 3 blocks/CU.
__global__ __launch_bounds__(256, 3) void dist_min_kernel(
        const __bf16* __restrict__ fbb, const unsigned char* __restrict__ mbt,
        const float* __restrict__ f2, const float* __restrict__ m2,
        unsigned int* __restrict__ nn) {
    __shared__ __align__(16) unsigned char lds[TILE_BYTES];
    const int tid  = threadIdx.x;
    const int lane = tid & 63;
    const int w    = tid >> 6;
    const int c16  = lane & 15;   // A-row16 / B-col16 / C-col
    const int kq   = lane >> 4;   // k-quarter (8 elems each)
    const int arow = blockIdx.x * BM + w * 64;

    // A fragments: afrag[mb][kk] = A[arow+mb*16+c16][kk*32 + kq*8 .. +7]
    bf16x8_t afrag[4][4];
    #pragma unroll
    for (int mb = 0; mb < 4; ++mb) {
        int row = arow + mb * 16 + c16;
        if (row >= N_FEAT) row = N_FEAT - 1;   // tail clamp (results discarded)
        #pragma unroll
        for (int kk = 0; kk < 4; ++kk)
            afrag[mb][kk] = *(const bf16x8_t*)(fbb + (size_t)row * DIM + kk * 32 + kq * 8);
    }

    float rmin[4][4];
    #pragma unroll
    for (int mb = 0; mb < 4; ++mb)
        #pragma unroll
        for (int j = 0; j < 4; ++j) rmin[mb][j] = INFINITY;

    const int tile0 = blockIdx.y * TPC;
    for (int t = 0; t < TPC; ++t) {
        const int tile = tile0 + t;
        // Stage 32KB tile: linear global -> linear LDS (pre-tiled layout).
        const unsigned char* src = mbt + (size_t)tile * TILE_BYTES + tid * 16;
        unsigned char* dst = lds + tid * 16;
        #pragma unroll
        for (int i = 0; i < 8; ++i)
            __builtin_amdgcn_global_load_lds((g_u32*)(src + i * 4096),
                                             (l_u32*)(dst + i * 4096), 16, 0, 0);
        __syncthreads();   // vmcnt(0) drain: tile staged

        const int c0 = tile * BN;
        float m2v[8];
        #pragma unroll
        for (int n = 0; n < 8; ++n) m2v[n] = m2[c0 + n * 16 + c16];

        #pragma unroll
        for (int n = 0; n < 8; ++n) {
            bf16x8_t b[4];
            #pragma unroll
            for (int kk = 0; kk < 4; ++kk)
                b[kk] = *(const bf16x8_t*)(lds + (kk * 4 + kq) * 2048 + (n * 16 + c16) * 16);
            f32x4_t acc[4];
            #pragma unroll
            for (int mb = 0; mb < 4; ++mb) {
                acc[mb] = (f32x4_t){0.f, 0.f, 0.f, 0.f};
                #pragma unroll
                for (int kk = 0; kk < 4; ++kk)
                    acc[mb] = __builtin_amdgcn_mfma_f32_16x16x32_bf16(afrag[mb][kk], b[kk],
                                                                      acc[mb], 0, 0, 0);
            }
            #pragma unroll
            for (int mb = 0; mb < 4; ++mb)
                #pragma unroll
                for (int j = 0; j < 4; ++j)
                    rmin[mb][j] = fminf(rmin[mb][j], fmaf(-2.f, acc[mb][j], m2v[n]));
        }
        __syncthreads();   // all reads done before next tile's stage overwrites
    }

    // Epilogue: min across the 16 col-lanes, add f2, one atomic per row.
    #pragma unroll
    for (int mb = 0; mb < 4; ++mb)
        #pragma unroll
        for (int j = 0; j < 4; ++j) {
            float v = rmin[mb][j];
            v = fminf(v, __shfl_xor(v, 1));
            v = fminf(v, __shfl_xor(v, 2));
            v = fminf(v, __shfl_xor(v, 4));
            v = fminf(v, __shfl_xor(v, 8));
            if (c16 == 0) {
                int row = arow + mb * 16 + kq * 4 + j;
                if (row < N_FEAT)
                    atomicMin(nn + row, __float_as_uint(v + f2[row]));
            }
        }
}

// Fused per-image max + bilinear upsample. One block per image; nn patch
// grid staged once in LDS, then 224x224 bilinear from LDS.
__global__ __launch_bounds__(256) void finalize_kernel(const unsigned int* __restrict__ nn,
                                                       float* __restrict__ out_scores,
                                                       float* __restrict__ out_up) {
    __shared__ float tile[PH * PW];
    __shared__ float wmax[4];
    const int b = blockIdx.x;
    const int tid = threadIdx.x;
    float v = -INFINITY;
    for (int i = tid; i < PH * PW; i += 256) {
        float x = __uint_as_float(nn[b * PH * PW + i]);
        tile[i] = x;
        v = fmaxf(v, x);
    }
    #pragma unroll
    for (int m = 1; m < 64; m <<= 1) v = fmaxf(v, __shfl_xor(v, m));
    if ((tid & 63) == 0) wmax[tid >> 6] = v;
    __syncthreads();
    if (tid == 0)
        out_scores[b] = fmaxf(fmaxf(wmax[0], wmax[1]), fmaxf(wmax[2], wmax[3]));
    float* up = out_up + (size_t)b * IMG * IMG;
    for (int idx = tid; idx < IMG * IMG; idx += 256) {
        int y = idx / IMG;
        int x = idx - y * IMG;
        float sy = y * 0.125f - 0.4375f;
        float sx = x * 0.125f - 0.4375f;
        float fy = floorf(sy), fx = floorf(sx);
        float ty = sy - fy, tx = sx - fx;
        int y0 = (int)fy, x0 = (int)fx;
        int y1 = min(y0 + 1, PH - 1), x1 = min(x0 + 1, PW - 1);
        y0 = max(y0, 0); x0 = max(x0, 0);
        float v00 = tile[y0 * PW + x0];
        float v01 = tile[y0 * PW + x1];
        float v10 = tile[y1 * PW + x0];
        float v11 = tile[y1 * PW + x1];
        float a0 = v00 + tx * (v01 - v00);
        float a1 = v10 + tx * (v11 - v10);
        up[idx] = a0 + ty * (a1 - a0);
    }
}

extern "C" void kernel_launch(void* const* d_in, const int* in_sizes, int n_in,
                              void* d_out, int out_size, void* d_ws, size_t ws_size,
                              hipStream_t stream) {
    const float* feat = (const float*)d_in[0];   // [6272,128] f32
    const float* bank = (const float*)d_in[1];   // [30000,128] f32
    char* ws = (char*)d_ws;
    unsigned char* mbt = (unsigned char*)(ws + 0);     // 30080*128*2 = 7,700,480 (tiled)
    __bf16*        fbb = (__bf16*)(ws + 7700480);      // 6272*128*2  = 1,605,632
    float*         m2  = (float*)(ws + 9306112);       // 30080*4
    float*         f2  = (float*)(ws + 9426432);       // 6272*4
    unsigned int*  nn  = (unsigned int*)(ws + 9451520);// 6272*4
    float* out_scores = (float*)d_out;                 // [8]
    float* out_up     = out_scores + NB;               // [8,224,224]

    hipLaunchKernelGGL(prep_bank, dim3(M_PAD / 16), dim3(256), 0, stream, bank, mbt, m2);
    hipLaunchKernelGGL(prep_feat, dim3(N_FEAT / 4), dim3(256), 0, stream, feat, fbb, f2, nn);
    hipLaunchKernelGGL(dist_min_kernel, dim3((N_FEAT + BM - 1) / BM, CHUNKS), dim3(256), 0,
                       stream, fbb, mbt, f2, m2, nn);
    hipLaunchKernelGGL(finalize_kernel, dim3(NB), dim3(256), 0, stream, nn, out_scores, out_up);
}

// Round 9
// 75.531 us; speedup vs baseline: 20.6228x; 1.1335x over previous
//
#include <hip/hip_runtime.h>
#include <hip/hip_bf16.h>
#include <math.h>

#define N_FEAT 6272
#define DIM    128
#define M_BANK 30000
#define M_PAD  30080
#define NB     8
#define PH     28
#define PW     28
#define IMG    224
#define BM     256      // 4 waves x 64 rows (4 mb-blocks of 16)
#define BN     128      // bank cols per LDS tile
#define TPC    5
#define CHUNKS 47       // 47*5*128 = 30080
#define TILE_BYTES 32768

typedef __attribute__((ext_vector_type(8)))  __bf16 bf16x8_t;
typedef __attribute__((ext_vector_type(2)))  __bf16 bf16x2_t;
typedef __attribute__((ext_vector_type(4)))  float  f32x4_t;
typedef __attribute__((ext_vector_type(2)))  float  f32x2_t;

typedef const __attribute__((address_space(1))) unsigned int g_u32;
typedef __attribute__((address_space(3))) unsigned int l_u32;

// Bank prep: fp32 -> bf16, retiled into MFMA B-fragment order.
// Layout: tile t (128 cols) | k-slice s = k>>3 (16 slices) | col c (128) | 8 bf16.
// byte addr = t*32768 + s*2048 + c*16. Also per-row sum-of-squares (+inf pad).
__global__ __launch_bounds__(256) void prep_bank(const float* __restrict__ src,
                                                 unsigned char* __restrict__ mbt,
                                                 float* __restrict__ sq) {
    const int tid  = threadIdx.x;
    const int s    = tid & 15;          // k-slice
    const int rloc = tid >> 4;          // 16 rows per block
    const int r    = blockIdx.x * 16 + rloc;
    const bool valid = r < M_BANK;
    float x[8];
    if (valid) {
        f32x4_t v0 = *(const f32x4_t*)(src + (size_t)r * DIM + s * 8);
        f32x4_t v1 = *(const f32x4_t*)(src + (size_t)r * DIM + s * 8 + 4);
        x[0]=v0.x; x[1]=v0.y; x[2]=v0.z; x[3]=v0.w;
        x[4]=v1.x; x[5]=v1.y; x[6]=v1.z; x[7]=v1.w;
    } else {
        #pragma unroll
        for (int e = 0; e < 8; ++e) x[e] = 0.f;
    }
    float sum = 0.f;
    #pragma unroll
    for (int e = 0; e < 8; ++e) sum += x[e] * x[e];
    sum += __shfl_xor(sum, 1);
    sum += __shfl_xor(sum, 2);
    sum += __shfl_xor(sum, 4);
    sum += __shfl_xor(sum, 8);
    bf16x8_t p;
    #pragma unroll
    for (int e = 0; e < 8; ++e) p[e] = (__bf16)x[e];
    const size_t addr = (size_t)(r >> 7) * TILE_BYTES + s * 2048 + (r & 127) * 16;
    *(bf16x8_t*)(mbt + addr) = p;
    if (s == 0) sq[r] = valid ? sum : INFINITY;
}

// Feature prep: row-major bf16 + sum-of-squares + nn init (one wave per row).
__global__ __launch_bounds__(256) void prep_feat(const float* __restrict__ src,
                                                 __bf16* __restrict__ dst,
                                                 float* __restrict__ sq,
                                                 unsigned int* __restrict__ nn) {
    int wave = (blockIdx.x * blockDim.x + threadIdx.x) >> 6;
    int lane = threadIdx.x & 63;
    if (wave >= N_FEAT) return;
    f32x2_t v = *(const f32x2_t*)(src + (size_t)wave * DIM + lane * 2);
    float s = v.x * v.x + v.y * v.y;
    #pragma unroll
    for (int m = 1; m < 64; m <<= 1) s += __shfl_xor(s, m);
    bf16x2_t p; p.x = (__bf16)v.x; p.y = (__bf16)v.y;
    *(bf16x2_t*)(dst + (size_t)wave * DIM + lane * 2) = p;
    if (lane == 0) { sq[wave] = s; nn[wave] = 0x7f800000u; }
}

// r8 compute shape + minimum 2-phase double-buffer: STAGE(t+1) issued BEFORE
// compute(t); ONE __syncthreads per tile at the end, whose vmcnt(0) drain
// waits on loads issued ~2500 cycles earlier (already landed). 4 waves x
// 64 rows (4 mb-blocks of 16), 16x16x32 MFMA, full n-unroll.
__global__ __launch_bounds__(256, 2) void dist_min_kernel(
        const __bf16* __restrict__ fbb, const unsigned char* __restrict__ mbt,
        const float* __restrict__ f2, const float* __restrict__ m2,
        unsigned int* __restrict__ nn) {
    __shared__ __align__(16) unsigned char lds[2 * TILE_BYTES];
    const int tid  = threadIdx.x;
    const int lane = tid & 63;
    const int w    = tid >> 6;
    const int c16  = lane & 15;   // A-row16 / B-col16 / C-col
    const int kq   = lane >> 4;   // k-quarter (8 elems each)
    const int arow = blockIdx.x * BM + w * 64;

    // A fragments: afrag[mb][kk] = A[arow+mb*16+c16][kk*32 + kq*8 .. +7]
    bf16x8_t afrag[4][4];
    #pragma unroll
    for (int mb = 0; mb < 4; ++mb) {
        int row = arow + mb * 16 + c16;
        if (row >= N_FEAT) row = N_FEAT - 1;   // tail clamp (results discarded)
        #pragma unroll
        for (int kk = 0; kk < 4; ++kk)
            afrag[mb][kk] = *(const bf16x8_t*)(fbb + (size_t)row * DIM + kk * 32 + kq * 8);
    }

    float rmin[4][4];
    #pragma unroll
    for (int mb = 0; mb < 4; ++mb)
        #pragma unroll
        for (int j = 0; j < 4; ++j) rmin[mb][j] = INFINITY;

    const int tile0 = blockIdx.y * TPC;
    // prologue: stage tile0 into buffer 0
    {
        const unsigned char* src = mbt + (size_t)tile0 * TILE_BYTES + tid * 16;
        unsigned char* dst = lds + tid * 16;
        #pragma unroll
        for (int i = 0; i < 8; ++i)
            __builtin_amdgcn_global_load_lds((g_u32*)(src + i * 4096),
                                             (l_u32*)(dst + i * 4096), 16, 0, 0);
    }
    __syncthreads();

    int cur = 0;
    for (int t = 0; t < TPC; ++t) {
        const int tile = tile0 + t;
        // issue next tile's stage FIRST (lands while we compute this tile)
        if (t + 1 < TPC) {
            const unsigned char* src = mbt + (size_t)(tile + 1) * TILE_BYTES + tid * 16;
            unsigned char* dst = lds + (cur ^ 1) * TILE_BYTES + tid * 16;
            #pragma unroll
            for (int i = 0; i < 8; ++i)
                __builtin_amdgcn_global_load_lds((g_u32*)(src + i * 4096),
                                                 (l_u32*)(dst + i * 4096), 16, 0, 0);
        }
        const unsigned char* buf = lds + cur * TILE_BYTES;
        const int c0 = tile * BN;
        float m2v[8];
        #pragma unroll
        for (int n = 0; n < 8; ++n) m2v[n] = m2[c0 + n * 16 + c16];

        #pragma unroll
        for (int n = 0; n < 8; ++n) {
            bf16x8_t b[4];
            #pragma unroll
            for (int kk = 0; kk < 4; ++kk)
                b[kk] = *(const bf16x8_t*)(buf + (kk * 4 + kq) * 2048 + (n * 16 + c16) * 16);
            f32x4_t acc[4];
            #pragma unroll
            for (int mb = 0; mb < 4; ++mb) {
                acc[mb] = (f32x4_t){0.f, 0.f, 0.f, 0.f};
                #pragma unroll
                for (int kk = 0; kk < 4; ++kk)
                    acc[mb] = __builtin_amdgcn_mfma_f32_16x16x32_bf16(afrag[mb][kk], b[kk],
                                                                      acc[mb], 0, 0, 0);
            }
            #pragma unroll
            for (int mb = 0; mb < 4; ++mb)
                #pragma unroll
                for (int j = 0; j < 4; ++j)
                    rmin[mb][j] = fminf(rmin[mb][j], fmaf(-2.f, acc[mb][j], m2v[n]));
        }
        // ONE barrier per tile: drains t+1's stage (long landed) AND ensures
        // all waves finished reading buf[cur] before t+2 overwrites it.
        __syncthreads();
        cur ^= 1;
    }

    // Epilogue: min across the 16 col-lanes, add f2, one atomic per row.
    #pragma unroll
    for (int mb = 0; mb < 4; ++mb)
        #pragma unroll
        for (int j = 0; j < 4; ++j) {
            float v = rmin[mb][j];
            v = fminf(v, __shfl_xor(v, 1));
            v = fminf(v, __shfl_xor(v, 2));
            v = fminf(v, __shfl_xor(v, 4));
            v = fminf(v, __shfl_xor(v, 8));
            if (c16 == 0) {
                int row = arow + mb * 16 + kq * 4 + j;
                if (row < N_FEAT)
                    atomicMin(nn + row, __float_as_uint(v + f2[row]));
            }
        }
}

__global__ void image_max_kernel(const unsigned int* __restrict__ nn,
                                 float* __restrict__ out) {
    __shared__ float wmax[4];
    int b = blockIdx.x;
    int tid = threadIdx.x;
    float v = -INFINITY;
    for (int i = tid; i < PH * PW; i += 256)
        v = fmaxf(v, __uint_as_float(nn[b * PH * PW + i]));
    #pragma unroll
    for (int m = 1; m < 64; m <<= 1) v = fmaxf(v, __shfl_xor(v, m));
    if ((tid & 63) == 0) wmax[tid >> 6] = v;
    __syncthreads();
    if (tid == 0) out[b] = fmaxf(fmaxf(wmax[0], wmax[1]), fmaxf(wmax[2], wmax[3]));
}

// Half-pixel bilinear 28x28 -> 224x224 with edge clamp (== jax bilinear resize).
__global__ void upsample_kernel(const unsigned int* __restrict__ nn,
                                float* __restrict__ up) {
    int idx = blockIdx.x * 256 + threadIdx.x;
    if (idx >= NB * IMG * IMG) return;
    int b = idx / (IMG * IMG);
    int rem = idx - b * (IMG * IMG);
    int y = rem / IMG;
    int x = rem - y * IMG;
    float sy = y * 0.125f - 0.4375f;
    float sx = x * 0.125f - 0.4375f;
    float fy = floorf(sy), fx = floorf(sx);
    float ty = sy - fy, tx = sx - fx;
    int y0 = (int)fy, x0 = (int)fx;
    int y1 = min(y0 + 1, PH - 1), x1 = min(x0 + 1, PW - 1);
    y0 = max(y0, 0); x0 = max(x0, 0);
    const unsigned int* p = nn + b * PH * PW;
    float v00 = __uint_as_float(p[y0 * PW + x0]);
    float v01 = __uint_as_float(p[y0 * PW + x1]);
    float v10 = __uint_as_float(p[y1 * PW + x0]);
    float v11 = __uint_as_float(p[y1 * PW + x1]);
    float v0 = v00 + tx * (v01 - v00);
    float v1 = v10 + tx * (v11 - v10);
    up[idx] = v0 + ty * (v1 - v0);
}

extern "C" void kernel_launch(void* const* d_in, const int* in_sizes, int n_in,
                              void* d_out, int out_size, void* d_ws, size_t ws_size,
                              hipStream_t stream) {
    const float* feat = (const float*)d_in[0];   // [6272,128] f32
    const float* bank = (const float*)d_in[1];   // [30000,128] f32
    char* ws = (char*)d_ws;
    unsigned char* mbt = (unsigned char*)(ws + 0);     // 30080*128*2 = 7,700,480 (tiled)
    __bf16*        fbb = (__bf16*)(ws + 7700480);      // 6272*128*2  = 1,605,632
    float*         m2  = (float*)(ws + 9306112);       // 30080*4
    float*         f2  = (float*)(ws + 9426432);       // 6272*4
    unsigned int*  nn  = (unsigned int*)(ws + 9451520);// 6272*4
    float* out_scores = (float*)d_out;                 // [8]
    float* out_up     = out_scores + NB;               // [8,224,224]

    hipLaunchKernelGGL(prep_bank, dim3(M_PAD / 16), dim3(256), 0, stream, bank, mbt, m2);
    hipLaunchKernelGGL(prep_feat, dim3(N_FEAT / 4), dim3(256), 0, stream, feat, fbb, f2, nn);
    hipLaunchKernelGGL(dist_min_kernel, dim3((N_FEAT + BM - 1) / BM, CHUNKS), dim3(256), 0,
                       stream, fbb, mbt, f2, m2, nn);
    hipLaunchKernelGGL(image_max_kernel, dim3(NB), dim3(256), 0, stream, nn, out_scores);
    hipLaunchKernelGGL(upsample_kernel, dim3((NB * IMG * IMG + 255) / 256), dim3(256), 0,
                       stream, nn, out_up);
}

// Round 10
// 68.347 us; speedup vs baseline: 22.7905x; 1.1051x over previous
//
#include <hip/hip_runtime.h>
#include <hip/hip_bf16.h>
#include <math.h>

#define N_FEAT 6272
#define DIM    128
#define M_BANK 30000
#define M_PAD  30080
#define NB     8
#define PH     28
#define PW     28
#define IMG    224
#define BM     256        // 4 waves x 64 rows (4 mb-blocks of 16)
#define BN     64         // bank cols per LDS tile (16KB)
#define TPT    10         // tiles per chunk: 470 tiles / 47 chunks
#define CHUNKS 47
#define TILE_BYTES 16384  // 16 slices x 64 cols x 16B

typedef __attribute__((ext_vector_type(8)))  __bf16 bf16x8_t;
typedef __attribute__((ext_vector_type(2)))  __bf16 bf16x2_t;
typedef __attribute__((ext_vector_type(4)))  float  f32x4_t;
typedef __attribute__((ext_vector_type(2)))  float  f32x2_t;

typedef const __attribute__((address_space(1))) unsigned int g_u32;
typedef __attribute__((address_space(3))) unsigned int l_u32;

// Bank prep: fp32 -> bf16, retiled into MFMA B-fragment order, 64-col tiles.
// Layout: tile t (64 cols) | k-slice s = k>>3 (16) | col c (64) | 8 bf16.
// byte addr = t*16384 + s*1024 + c*16. Also per-row sum-of-squares (+inf pad).
__global__ __launch_bounds__(256) void prep_bank(const float* __restrict__ src,
                                                 unsigned char* __restrict__ mbt,
                                                 float* __restrict__ sq) {
    const int tid  = threadIdx.x;
    const int s    = tid & 15;          // k-slice
    const int rloc = tid >> 4;          // 16 rows per block
    const int r    = blockIdx.x * 16 + rloc;
    const bool valid = r < M_BANK;
    float x[8];
    if (valid) {
        f32x4_t v0 = *(const f32x4_t*)(src + (size_t)r * DIM + s * 8);
        f32x4_t v1 = *(const f32x4_t*)(src + (size_t)r * DIM + s * 8 + 4);
        x[0]=v0.x; x[1]=v0.y; x[2]=v0.z; x[3]=v0.w;
        x[4]=v1.x; x[5]=v1.y; x[6]=v1.z; x[7]=v1.w;
    } else {
        #pragma unroll
        for (int e = 0; e < 8; ++e) x[e] = 0.f;
    }
    float sum = 0.f;
    #pragma unroll
    for (int e = 0; e < 8; ++e) sum += x[e] * x[e];
    sum += __shfl_xor(sum, 1);
    sum += __shfl_xor(sum, 2);
    sum += __shfl_xor(sum, 4);
    sum += __shfl_xor(sum, 8);
    bf16x8_t p;
    #pragma unroll
    for (int e = 0; e < 8; ++e) p[e] = (__bf16)x[e];
    const size_t addr = (size_t)(r >> 6) * TILE_BYTES + s * 1024 + (r & 63) * 16;
    *(bf16x8_t*)(mbt + addr) = p;
    if (s == 0) sq[r] = valid ? sum : INFINITY;
}

// Feature prep: row-major bf16 + sum-of-squares + nn init (one wave per row).
__global__ __launch_bounds__(256) void prep_feat(const float* __restrict__ src,
                                                 __bf16* __restrict__ dst,
                                                 float* __restrict__ sq,
                                                 unsigned int* __restrict__ nn) {
    int wave = (blockIdx.x * blockDim.x + threadIdx.x) >> 6;
    int lane = threadIdx.x & 63;
    if (wave >= N_FEAT) return;
    f32x2_t v = *(const f32x2_t*)(src + (size_t)wave * DIM + lane * 2);
    float s = v.x * v.x + v.y * v.y;
    #pragma unroll
    for (int m = 1; m < 64; m <<= 1) s += __shfl_xor(s, m);
    bf16x2_t p; p.x = (__bf16)v.x; p.y = (__bf16)v.y;
    *(bf16x2_t*)(dst + (size_t)wave * DIM + lane * 2) = p;
    if (lane == 0) { sq[wave] = s; nn[wave] = 0x7f800000u; }
}

// r8 compute shape + clean 2-phase double-buffer at the SAME 32KB LDS budget:
// BN=64 tiles, 2 x 16KB buffers. m2 prefetched one tile ahead into registers
// (issued BEFORE that tile's stage loads) so no mid-tile vmcnt wait drains the
// stage queue (r9's bug). One barrier per tile; its vmcnt(0) drain waits on
// loads issued a full tile earlier (landed) -> drain ~ 0.
__global__ __launch_bounds__(256, 3) void dist_min_kernel(
        const __bf16* __restrict__ fbb, const unsigned char* __restrict__ mbt,
        const float* __restrict__ f2, const float* __restrict__ m2,
        unsigned int* __restrict__ nn) {
    __shared__ __align__(16) unsigned char lds[2 * TILE_BYTES];
    const int tid  = threadIdx.x;
    const int lane = tid & 63;
    const int w    = tid >> 6;
    const int c16  = lane & 15;   // A-row16 / B-col16 / C-col
    const int kq   = lane >> 4;   // k-quarter (8 elems each)
    const int arow = blockIdx.x * BM + w * 64;

    // A fragments: afrag[mb][kk] = A[arow+mb*16+c16][kk*32 + kq*8 .. +7]
    bf16x8_t afrag[4][4];
    #pragma unroll
    for (int mb = 0; mb < 4; ++mb) {
        int row = arow + mb * 16 + c16;
        if (row >= N_FEAT) row = N_FEAT - 1;   // tail clamp (results discarded)
        #pragma unroll
        for (int kk = 0; kk < 4; ++kk)
            afrag[mb][kk] = *(const bf16x8_t*)(fbb + (size_t)row * DIM + kk * 32 + kq * 8);
    }

    float rmin[4][4];
    #pragma unroll
    for (int mb = 0; mb < 4; ++mb)
        #pragma unroll
        for (int j = 0; j < 4; ++j) rmin[mb][j] = INFINITY;

    const int tile0 = blockIdx.y * TPT;

#define STAGE(tile_idx, bufsel)                                                      \
    {   const unsigned char* sp_ = mbt + (size_t)(tile_idx) * TILE_BYTES + tid * 16; \
        unsigned char* dp_ = lds + (bufsel) * TILE_BYTES + tid * 16;                 \
        _Pragma("unroll")                                                            \
        for (int i_ = 0; i_ < 4; ++i_)                                               \
            __builtin_amdgcn_global_load_lds((g_u32*)(sp_ + i_ * 4096),              \
                                             (l_u32*)(dp_ + i_ * 4096), 16, 0, 0); }

    // prologue: m2 for tile0, then stage tile0 -> buf0
    float m2cur[4];
    #pragma unroll
    for (int n = 0; n < 4; ++n) m2cur[n] = m2[tile0 * BN + n * 16 + c16];
    STAGE(tile0, 0);
    __syncthreads();

    int cur = 0;
    #pragma unroll 1
    for (int t = 0; t < TPT; ++t) {
        float m2next[4];
        if (t + 1 < TPT) {
            // m2 prefetch FIRST (oldest in VMEM FIFO), then stage issues.
            #pragma unroll
            for (int n = 0; n < 4; ++n)
                m2next[n] = m2[(tile0 + t + 1) * BN + n * 16 + c16];
            STAGE(tile0 + t + 1, cur ^ 1);
        }
        const unsigned char* buf = lds + cur * TILE_BYTES;
        #pragma unroll
        for (int n = 0; n < 4; ++n) {
            bf16x8_t b[4];
            #pragma unroll
            for (int kk = 0; kk < 4; ++kk)
                b[kk] = *(const bf16x8_t*)(buf + (kk * 4 + kq) * 1024 + (n * 16 + c16) * 16);
            f32x4_t acc[4];
            #pragma unroll
            for (int mb = 0; mb < 4; ++mb) {
                acc[mb] = (f32x4_t){0.f, 0.f, 0.f, 0.f};
                #pragma unroll
                for (int kk = 0; kk < 4; ++kk)
                    acc[mb] = __builtin_amdgcn_mfma_f32_16x16x32_bf16(afrag[mb][kk], b[kk],
                                                                      acc[mb], 0, 0, 0);
            }
            #pragma unroll
            for (int mb = 0; mb < 4; ++mb)
                #pragma unroll
                for (int j = 0; j < 4; ++j)
                    rmin[mb][j] = fminf(rmin[mb][j], fmaf(-2.f, acc[mb][j], m2cur[n]));
        }
        // ONE barrier/tile: next tile's stage long landed; buf[cur] free to reuse.
        __syncthreads();
        if (t + 1 < TPT) {
            #pragma unroll
            for (int n = 0; n < 4; ++n) m2cur[n] = m2next[n];
        }
        cur ^= 1;
    }
#undef STAGE

    // Epilogue: min across the 16 col-lanes, add f2, one atomic per row.
    #pragma unroll
    for (int mb = 0; mb < 4; ++mb)
        #pragma unroll
        for (int j = 0; j < 4; ++j) {
            float v = rmin[mb][j];
            v = fminf(v, __shfl_xor(v, 1));
            v = fminf(v, __shfl_xor(v, 2));
            v = fminf(v, __shfl_xor(v, 4));
            v = fminf(v, __shfl_xor(v, 8));
            if (c16 == 0) {
                int row = arow + mb * 16 + kq * 4 + j;
                if (row < N_FEAT)
                    atomicMin(nn + row, __float_as_uint(v + f2[row]));
            }
        }
}

// Merged finalize: blocks 0..(NB*IMG*IMG/256-1) do bilinear upsample;
// the last NB blocks compute per-image max. One launch instead of two.
#define UP_BLOCKS ((NB * IMG * IMG) / 256)   // 1568
__global__ __launch_bounds__(256) void finalize_kernel(const unsigned int* __restrict__ nn,
                                                       float* __restrict__ out_scores,
                                                       float* __restrict__ out_up) {
    if (blockIdx.x >= UP_BLOCKS) {
        __shared__ float wmax[4];
        int b = blockIdx.x - UP_BLOCKS;
        int tid = threadIdx.x;
        float v = -INFINITY;
        for (int i = tid; i < PH * PW; i += 256)
            v = fmaxf(v, __uint_as_float(nn[b * PH * PW + i]));
        #pragma unroll
        for (int m = 1; m < 64; m <<= 1) v = fmaxf(v, __shfl_xor(v, m));
        if ((tid & 63) == 0) wmax[tid >> 6] = v;
        __syncthreads();
        if (tid == 0)
            out_scores[b] = fmaxf(fmaxf(wmax[0], wmax[1]), fmaxf(wmax[2], wmax[3]));
        return;
    }
    int idx = blockIdx.x * 256 + threadIdx.x;
    int b = idx / (IMG * IMG);
    int rem = idx - b * (IMG * IMG);
    int y = rem / IMG;
    int x = rem - y * IMG;
    float sy = y * 0.125f - 0.4375f;
    float sx = x * 0.125f - 0.4375f;
    float fy = floorf(sy), fx = floorf(sx);
    float ty = sy - fy, tx = sx - fx;
    int y0 = (int)fy, x0 = (int)fx;
    int y1 = min(y0 + 1, PH - 1), x1 = min(x0 + 1, PW - 1);
    y0 = max(y0, 0); x0 = max(x0, 0);
    const unsigned int* p = nn + b * PH * PW;
    float v00 = __uint_as_float(p[y0 * PW + x0]);
    float v01 = __uint_as_float(p[y0 * PW + x1]);
    float v10 = __uint_as_float(p[y1 * PW + x0]);
    float v11 = __uint_as_float(p[y1 * PW + x1]);
    float v0 = v00 + tx * (v01 - v00);
    float v1 = v10 + tx * (v11 - v10);
    out_up[idx] = v0 + ty * (v1 - v0);
}

extern "C" void kernel_launch(void* const* d_in, const int* in_sizes, int n_in,
                              void* d_out, int out_size, void* d_ws, size_t ws_size,
                              hipStream_t stream) {
    const float* feat = (const float*)d_in[0];   // [6272,128] f32
    const float* bank = (const float*)d_in[1];   // [30000,128] f32
    char* ws = (char*)d_ws;
    unsigned char* mbt = (unsigned char*)(ws + 0);     // 30080*128*2 = 7,700,480 (tiled)
    __bf16*        fbb = (__bf16*)(ws + 7700480);      // 6272*128*2  = 1,605,632
    float*         m2  = (float*)(ws + 9306112);       // 30080*4
    float*         f2  = (float*)(ws + 9426432);       // 6272*4
    unsigned int*  nn  = (unsigned int*)(ws + 9451520);// 6272*4
    float* out_scores = (float*)d_out;                 // [8]
    float* out_up     = out_scores + NB;               // [8,224,224]

    hipLaunchKernelGGL(prep_bank, dim3(M_PAD / 16), dim3(256), 0, stream, bank, mbt, m2);
    hipLaunchKernelGGL(prep_feat, dim3(N_FEAT / 4), dim3(256), 0, stream, feat, fbb, f2, nn);
    hipLaunchKernelGGL(dist_min_kernel, dim3((N_FEAT + BM - 1) / BM, CHUNKS), dim3(256), 0,
                       stream, fbb, mbt, f2, m2, nn);
    hipLaunchKernelGGL(finalize_kernel, dim3(UP_BLOCKS + NB), dim3(256), 0, stream,
                       nn, out_scores, out_up);
}